// Round 10
// baseline (41.728 us; speedup 1.0000x reference)
//
#include <hip/hip_runtime.h>
#include <math.h>

#define S_IMG 160
#define NPIX (S_IMG * S_IMG)   // 25600
#define NF 4096
#define NV 1986                // vertices in the uv-sphere
#define TS 16                  // tile size 16x16
#define NTX 10                 // tiles per row
#define NTILE 100
#define CAP NF                 // per-tile survivor capacity (faces)
#define INV_LN2 1.4426950408889634f
#define CULL_THRESH -25.0f     // 2^d < 2^-25 => fma(P,e,P) == P bitwise (P>=1)

#define ROT_EPS 6.123234e-17f
#define CAM_Z 2.732f
#define VIEW_TAN 0.5773502691896258f

#if __has_builtin(__builtin_amdgcn_exp2f)
#define EXP2F(x) __builtin_amdgcn_exp2f(x)
#else
#define EXP2F(x) exp2f(x)
#endif

// One block per 16x16 tile; fused setup+cull+cover+finish.
//  phase 0: project all verts into LDS (rcp, not IEEE div)
//  phase 1: cull + ordered ballot-compaction of 9 edge coefficients into the
//           block-private global list, padded to a 64-multiple with dummies
//           (dmin=-64 -> e=2^-64: bitwise no-op on fma(P,e,P), inf-safe)
//  phase 2: wave w covers chunks k = w, w+8, ... via BLOCK-UNIFORM global
//           loads (same addr across lanes -> broadcast L2 request, zero DS
//           traffic in the hot loop; this was R8's DS-pipe bottleneck)
//  phase 3: cross-wave fixed-order product -> image + tile SSE
__global__ void __launch_bounds__(512) mega(const float* __restrict__ verts,
                                            const int* __restrict__ faces,
                                            float* __restrict__ list,
                                            const float* __restrict__ img_ref,
                                            float* __restrict__ out,
                                            float* __restrict__ bsums) {
    __shared__ float2 sverts[NV];
    __shared__ float pacc[8][256];
    __shared__ float red[8];
    __shared__ int wcnt[8];

    const int t = blockIdx.x;
    const int tid = threadIdx.x;
    const int wid = tid >> 6;
    const int lane = tid & 63;

    // ---- phase 0: project vertices once ----
    for (int i = tid; i < NV; i += 512) {
        float x = verts[3 * i], y = verts[3 * i + 1], z = verts[3 * i + 2];
        float vx = fmaf(ROT_EPS, x, z);
        float vz = fmaf(ROT_EPS, z, -x) + CAM_Z;
        float inv = __builtin_amdgcn_rcpf(vz * VIEW_TAN);
        sverts[i] = make_float2(fmaf(vx * inv, 80.0f, 80.0f),
                                fmaf(y * inv, 80.0f, 80.0f));
    }
    __syncthreads();

    // ---- phase 1: cull + compact ----
    const float cx = (float)((t % NTX) * TS) + 8.0f;   // centers span +-7.5
    const float cy = (float)((t / NTX) * TS) + 8.0f;
    float* mylist = list + (size_t)t * CAP * 12;
    int base = 0;

    for (int r = 0; r < NF / 512; ++r) {
        int f = r * 512 + tid;
        int i0 = faces[3 * f], i1 = faces[3 * f + 1], i2 = faces[3 * f + 2];
        float2 a = sverts[i0];
        float2 b = sverts[i1];
        float2 c = sverts[i2];
        float area = (b.x - a.x) * (c.y - a.y) - (b.y - a.y) * (c.x - a.x);
        float sg = (area >= 0.0f) ? INV_LN2 : -INV_LN2;
        bool valid = fabsf(area) > 1e-6f;

        float o[9];
        float umin = 1e30f;
        float2 p0s[3] = {a, b, c};
        float2 p1s[3] = {b, c, a};
#pragma unroll
        for (int e = 0; e < 3; ++e) {
            float dx = p1s[e].x - p0s[e].x;
            float dy = p1s[e].y - p0s[e].y;
            float dd = fmaf(dx, dx, dy * dy);
            float s = sg * __builtin_amdgcn_rsqf(dd);   // 1/|edge| ~1ulp
            float A = valid ? (-dy * s) : 0.0f;
            float B = valid ? (dx * s) : 0.0f;
            float C = valid ? ((dy * p0s[e].x - dx * p0s[e].y) * s) : -1e30f;
            o[3 * e + 0] = A;
            o[3 * e + 1] = B;
            o[3 * e + 2] = C;
            float bound = fmaf(fabsf(A) + fabsf(B), 7.5f, fmaf(A, cx, fmaf(B, cy, C)));
            umin = fminf(umin, valid ? bound : -1e30f);
        }
        bool pred = umin >= CULL_THRESH;
        unsigned long long m = __ballot(pred);
        int wpop = __popcll(m);
        int prefix = __popcll(m & ((1ull << lane) - 1ull));

        __syncthreads();                 // protect wcnt vs previous round
        if (lane == 0) wcnt[wid] = wpop;
        __syncthreads();
        int off = base;
#pragma unroll
        for (int w = 0; w < 8; ++w) {
            int cw = wcnt[w];
            if (w < wid) off += cw;
            base += cw;                  // running total, identical in all threads
        }
        off += prefix;
        if (pred) {
            float4* dst = (float4*)(mylist + (size_t)off * 12);
            dst[0] = make_float4(o[0], o[1], o[2], o[3]);
            dst[1] = make_float4(o[4], o[5], o[6], o[7]);
            dst[2] = make_float4(o[8], 0.0f, 0.0f, 0.0f);
        }
    }
    __syncthreads();

    const int cnt = base;
    const int nkt = (cnt + 63) >> 6;     // 0 allowed (empty tile)
    {
        int padcnt = nkt * 64 - cnt;
        for (int i = tid; i < padcnt; i += 512) {
            float4* dst = (float4*)(mylist + (size_t)(cnt + i) * 12);
            dst[0] = make_float4(0.0f, 0.0f, -64.0f, 0.0f);
            dst[1] = make_float4(0.0f, -64.0f, 0.0f, 0.0f);
            dst[2] = make_float4(-64.0f, 0.0f, 0.0f, 0.0f);
        }
    }
    __syncthreads();                     // list fully written (same block reads it)

    // ---- phase 2: cover, block-uniform loads, register accumulation ----
    const int colL = lane & 15;
    const int rowL = (lane >> 4) * 4;
    const float px = (float)((t % NTX) * TS + colL) + 0.5f;
    const float py0 = (float)((t / NTX) * TS + rowL) + 0.5f;
    const float py1 = py0 + 1.0f, py2 = py0 + 2.0f, py3 = py0 + 3.0f;

    float P0 = 1.0f, P1 = 1.0f, P2 = 1.0f, P3 = 1.0f;

    for (int k = wid; k < nkt; k += 8) {
        const float* fptr = mylist + (size_t)k * 64 * 12;
#pragma unroll 4
        for (int j = 0; j < 64; ++j) {
            float4 c0 = *(const float4*)(fptr + 12 * j);
            float4 c1 = *(const float4*)(fptr + 12 * j + 4);
            float4 c2 = *(const float4*)(fptr + 12 * j + 8);
            float b1 = fmaf(c0.x, px, c0.z);
            float b2 = fmaf(c0.w, px, c1.y);
            float b3 = fmaf(c1.z, px, c2.x);
            {
                float d1 = fmaf(c0.y, py0, b1), d2 = fmaf(c1.x, py0, b2), d3 = fmaf(c1.w, py0, b3);
                float e = EXP2F(fminf(fminf(d1, d2), d3));
                P0 = fmaf(P0, e, P0);
            }
            {
                float d1 = fmaf(c0.y, py1, b1), d2 = fmaf(c1.x, py1, b2), d3 = fmaf(c1.w, py1, b3);
                float e = EXP2F(fminf(fminf(d1, d2), d3));
                P1 = fmaf(P1, e, P1);
            }
            {
                float d1 = fmaf(c0.y, py2, b1), d2 = fmaf(c1.x, py2, b2), d3 = fmaf(c1.w, py2, b3);
                float e = EXP2F(fminf(fminf(d1, d2), d3));
                P2 = fmaf(P2, e, P2);
            }
            {
                float d1 = fmaf(c0.y, py3, b1), d2 = fmaf(c1.x, py3, b2), d3 = fmaf(c1.w, py3, b3);
                float e = EXP2F(fminf(fminf(d1, d2), d3));
                P3 = fmaf(P3, e, P3);
            }
        }
    }

    // wave partial -> LDS
    pacc[wid][rowL * 16 + colL] = __builtin_amdgcn_rcpf(P0);
    pacc[wid][(rowL + 1) * 16 + colL] = __builtin_amdgcn_rcpf(P1);
    pacc[wid][(rowL + 2) * 16 + colL] = __builtin_amdgcn_rcpf(P2);
    pacc[wid][(rowL + 3) * 16 + colL] = __builtin_amdgcn_rcpf(P3);
    __syncthreads();

    // ---- phase 3: fixed-order combine + image + SSE ----
    float sq = 0.0f;
    if (tid < 256) {
        float prod = 1.0f;
#pragma unroll
        for (int w = 0; w < 8; ++w) prod *= pacc[w][tid];
        float img = 1.0f - prod;
        int col = (t % NTX) * TS + (tid & 15);
        int row = (t / NTX) * TS + (tid >> 4);
        int p = row * S_IMG + col;
        out[p] = img;
        float d = img - img_ref[p];
        sq = d * d;
    }
#pragma unroll
    for (int off = 32; off > 0; off >>= 1) sq += __shfl_down(sq, off);
    if (lane == 0) red[wid] = sq;
    __syncthreads();
    if (tid == 0) {
        float s = ((red[0] + red[1]) + (red[2] + red[3])) +
                  ((red[4] + red[5]) + (red[6] + red[7]));
        bsums[t] = s;
    }
}

// Fixed-order reduction of 100 tile SSEs -> loss (lane covers i and i+64).
__global__ void __launch_bounds__(64) loss_kernel(const float* __restrict__ bsums,
                                                  float* __restrict__ loss_out) {
    int lane = threadIdx.x;
    float v = 0.0f;
    if (lane < NTILE) v = bsums[lane];
    if (lane + 64 < NTILE) v += bsums[lane + 64];
#pragma unroll
    for (int off = 32; off > 0; off >>= 1) v += __shfl_down(v, off);
    if (lane == 0) loss_out[0] = v;
}

extern "C" void kernel_launch(void* const* d_in, const int* in_sizes, int n_in,
                              void* d_out, int out_size, void* d_ws, size_t ws_size,
                              hipStream_t stream) {
    const float* verts = (const float*)d_in[0];
    const int* faces = (const int*)d_in[1];
    const float* img_ref = (const float*)d_in[2];
    float* out = (float*)d_out;

    float* list = (float*)d_ws;                        // 100*4096*12 f = 19.66 MB
    float* bsums = list + (size_t)NTILE * CAP * 12;    // 100 floats

    mega<<<NTILE, 512, 0, stream>>>(verts, faces, list, img_ref, out, bsums);
    loss_kernel<<<1, 64, 0, stream>>>(bsums, out + NPIX);
}

// Round 11
// 38.731 us; speedup vs baseline: 1.0774x; 1.0774x over previous
//
#include <hip/hip_runtime.h>
#include <math.h>

#define S_IMG 160
#define NPIX (S_IMG * S_IMG)   // 25600
#define NF 4096
#define NV 1986                // vertices in the uv-sphere
#define TS 16                  // tile size 16x16
#define NTX 10                 // tiles per row
#define NTILE 100
#define CAP NF                 // per-tile survivor capacity (faces)
#define MAXK 64                // max 64-face chunks per tile
#define NBLK 512               // cover blocks (4 waves each -> 2048 waves)
#define INV_LN2 1.4426950408889634f
#define CULL_THRESH -25.0f     // 2^d < 2^-25 => fma(P,e,P) == P bitwise (P>=1)

#define ROT_EPS 6.123234e-17f
#define CAM_Z 2.732f
#define VIEW_TAN 0.5773502691896258f

#if __has_builtin(__builtin_amdgcn_exp2f)
#define EXP2F(x) __builtin_amdgcn_exp2f(x)
#else
#define EXP2F(x) exp2f(x)
#endif

// K1: one block per 16x16 tile. Project verts to LDS, cull + ordered ballot
// compaction of 9 edge coefficients (pre-scaled by log2 e), pad to a
// 64-multiple with dummy faces (dmin=-64 -> e=2^-64: bitwise no-op on
// fma(P,e,P) for all finite P>=1, inf-safe).
__global__ void __launch_bounds__(512) setup_cull(const float* __restrict__ verts,
                                                  const int* __restrict__ faces,
                                                  float* __restrict__ list,
                                                  int* __restrict__ nk_arr) {
    __shared__ float2 sverts[NV];
    __shared__ int wcnt[8];

    const int t = blockIdx.x;
    const int tid = threadIdx.x;
    const int wid = tid >> 6;
    const int lane = tid & 63;

    for (int i = tid; i < NV; i += 512) {
        float x = verts[3 * i], y = verts[3 * i + 1], z = verts[3 * i + 2];
        float vx = fmaf(ROT_EPS, x, z);
        float vz = fmaf(ROT_EPS, z, -x) + CAM_Z;
        float inv = __builtin_amdgcn_rcpf(vz * VIEW_TAN);
        sverts[i] = make_float2(fmaf(vx * inv, 80.0f, 80.0f),
                                fmaf(y * inv, 80.0f, 80.0f));
    }
    __syncthreads();

    const float cx = (float)((t % NTX) * TS) + 8.0f;   // centers span +-7.5
    const float cy = (float)((t / NTX) * TS) + 8.0f;
    float* mylist = list + (size_t)t * CAP * 12;
    int base = 0;

    for (int r = 0; r < NF / 512; ++r) {
        int f = r * 512 + tid;
        int i0 = faces[3 * f], i1 = faces[3 * f + 1], i2 = faces[3 * f + 2];
        float2 a = sverts[i0];
        float2 b = sverts[i1];
        float2 c = sverts[i2];
        float area = (b.x - a.x) * (c.y - a.y) - (b.y - a.y) * (c.x - a.x);
        float sg = (area >= 0.0f) ? INV_LN2 : -INV_LN2;
        bool valid = fabsf(area) > 1e-6f;

        float o[9];
        float umin = 1e30f;
        float2 p0s[3] = {a, b, c};
        float2 p1s[3] = {b, c, a};
#pragma unroll
        for (int e = 0; e < 3; ++e) {
            float dx = p1s[e].x - p0s[e].x;
            float dy = p1s[e].y - p0s[e].y;
            float dd = fmaf(dx, dx, dy * dy);
            float s = sg * __builtin_amdgcn_rsqf(dd);   // 1/|edge| ~1ulp
            float A = valid ? (-dy * s) : 0.0f;
            float B = valid ? (dx * s) : 0.0f;
            float C = valid ? ((dy * p0s[e].x - dx * p0s[e].y) * s) : -1e30f;
            o[3 * e + 0] = A;
            o[3 * e + 1] = B;
            o[3 * e + 2] = C;
            float bound = fmaf(fabsf(A) + fabsf(B), 7.5f, fmaf(A, cx, fmaf(B, cy, C)));
            umin = fminf(umin, valid ? bound : -1e30f);
        }
        bool pred = umin >= CULL_THRESH;
        unsigned long long m = __ballot(pred);
        int wpop = __popcll(m);
        int prefix = __popcll(m & ((1ull << lane) - 1ull));

        __syncthreads();                 // protect wcnt vs previous round
        if (lane == 0) wcnt[wid] = wpop;
        __syncthreads();
        int off = base;
#pragma unroll
        for (int w = 0; w < 8; ++w) {
            int cw = wcnt[w];
            if (w < wid) off += cw;
            base += cw;                  // running total, identical in all threads
        }
        off += prefix;
        if (pred) {
            float4* dst = (float4*)(mylist + (size_t)off * 12);
            dst[0] = make_float4(o[0], o[1], o[2], o[3]);
            dst[1] = make_float4(o[4], o[5], o[6], o[7]);
            dst[2] = make_float4(o[8], 0.0f, 0.0f, 0.0f);
        }
    }
    __syncthreads();

    const int cnt = base;
    const int nkt = (cnt + 63) >> 6;     // 0 allowed (empty tile)
    int padcnt = nkt * 64 - cnt;
    for (int i = tid; i < padcnt; i += 512) {
        float4* dst = (float4*)(mylist + (size_t)(cnt + i) * 12);
        dst[0] = make_float4(0.0f, 0.0f, -64.0f, 0.0f);
        dst[1] = make_float4(0.0f, -64.0f, 0.0f, 0.0f);
        dst[2] = make_float4(-64.0f, 0.0f, 0.0f, 0.0f);
    }
    if (tid == 0) nk_arr[t] = nkt;
}

// K1b: single tiny block. Serial exclusive scan of nk_arr (100 values, cheap,
// deterministic), then parallel emission of the flat item list
// items[p] = (t<<8)|k in (t,k)-ascending order. items_meta[0] = NIT.
__global__ void __launch_bounds__(128) build_items(const int* __restrict__ nk_arr,
                                                   int* __restrict__ cumk,
                                                   int* __restrict__ items) {
    __shared__ int scum[NTILE + 1];
    if (threadIdx.x == 0) {
        int acc = 0;
        for (int t = 0; t < NTILE; ++t) { scum[t] = acc; acc += nk_arr[t]; }
        scum[NTILE] = acc;
        cumk[NTILE] = acc;
    }
    __syncthreads();
    for (int t = threadIdx.x; t < NTILE; t += 128) {
        int b = scum[t], n = scum[t + 1] - b;
        cumk[t] = b;
        for (int k = 0; k < n; ++k) items[b + k] = (t << 8) | k;
    }
}

// K2: fixed grid NBLK x 256 (4 waves/block, ~2/SIMD chip-wide). Waves
// grid-stride the flat item list; every item = 64 faces for one tile ->
// uniform cost, near-perfect balance. Per item: coalesced per-lane stage of
// 192 float4 into the wave's LDS slot, then 64 uniform-broadcast ds_reads.
__global__ void __launch_bounds__(256) cover(const float* __restrict__ list,
                                             const int* __restrict__ cumk,
                                             const int* __restrict__ items,
                                             float* __restrict__ partials) {
    __shared__ float4 slot[4][64 * 3];   // 12 KB
    const int wid = threadIdx.x >> 6;
    const int lane = threadIdx.x & 63;
    const int NIT = cumk[NTILE];
    const int NW = NBLK * 4;
    float4* myslot = slot[wid];

    for (int p = blockIdx.x * 4 + wid; p < NIT; p += NW) {
        int item = items[p];
        int t = item >> 8, k = item & 255;

        const float4* src = (const float4*)(list + ((size_t)t * CAP + (size_t)k * 64) * 12);
#pragma unroll
        for (int i = 0; i < 3; ++i) myslot[lane + i * 64] = src[lane + i * 64];
        asm volatile("s_waitcnt lgkmcnt(0)" ::: "memory");  // wave-private slot

        const int colL = lane & 15;
        const int rowL = (lane >> 4) * 4;
        const float px = (float)((t % NTX) * TS + colL) + 0.5f;
        const float py0 = (float)((t / NTX) * TS + rowL) + 0.5f;
        const float py1 = py0 + 1.0f, py2 = py0 + 2.0f, py3 = py0 + 3.0f;

        float P0 = 1.0f, P1 = 1.0f, P2 = 1.0f, P3 = 1.0f;
        for (int j = 0; j < 64; ++j) {
            float4 c0 = myslot[3 * j];
            float4 c1 = myslot[3 * j + 1];
            float4 c2 = myslot[3 * j + 2];
            float b1 = fmaf(c0.x, px, c0.z);
            float b2 = fmaf(c0.w, px, c1.y);
            float b3 = fmaf(c1.z, px, c2.x);
            {
                float d1 = fmaf(c0.y, py0, b1), d2 = fmaf(c1.x, py0, b2), d3 = fmaf(c1.w, py0, b3);
                float e = EXP2F(fminf(fminf(d1, d2), d3));
                P0 = fmaf(P0, e, P0);
            }
            {
                float d1 = fmaf(c0.y, py1, b1), d2 = fmaf(c1.x, py1, b2), d3 = fmaf(c1.w, py1, b3);
                float e = EXP2F(fminf(fminf(d1, d2), d3));
                P1 = fmaf(P1, e, P1);
            }
            {
                float d1 = fmaf(c0.y, py2, b1), d2 = fmaf(c1.x, py2, b2), d3 = fmaf(c1.w, py2, b3);
                float e = EXP2F(fminf(fminf(d1, d2), d3));
                P2 = fmaf(P2, e, P2);
            }
            {
                float d1 = fmaf(c0.y, py3, b1), d2 = fmaf(c1.x, py3, b2), d3 = fmaf(c1.w, py3, b3);
                float e = EXP2F(fminf(fminf(d1, d2), d3));
                P3 = fmaf(P3, e, P3);
            }
        }
        asm volatile("" ::: "memory");   // keep reads before next stage overwrite

        size_t base = ((size_t)t * MAXK + k) * 256 + (size_t)rowL * 16 + colL;
        partials[base] = __builtin_amdgcn_rcpf(P0);
        partials[base + 16] = __builtin_amdgcn_rcpf(P1);
        partials[base + 32] = __builtin_amdgcn_rcpf(P2);
        partials[base + 48] = __builtin_amdgcn_rcpf(P3);
    }
}

// K3: one block per tile (256 thr = 256 px). Fixed-k-order product over live
// layers, image + tile SSE (deterministic tree).
__global__ void __launch_bounds__(256) finish(const float* __restrict__ partials,
                                              const int* __restrict__ nk_arr,
                                              const float* __restrict__ img_ref,
                                              float* __restrict__ out,
                                              float* __restrict__ bsums) {
    const int t = blockIdx.x;
    const int tid = threadIdx.x;
    const int nkt = nk_arr[t];
    float prod = 1.0f;
    for (int k = 0; k < nkt; ++k) prod *= partials[((size_t)t * MAXK + k) * 256 + tid];
    float img = 1.0f - prod;
    int col = (t % NTX) * TS + (tid & 15);
    int row = (t / NTX) * TS + (tid >> 4);
    int p = row * S_IMG + col;
    out[p] = img;
    float d = img - img_ref[p];
    float sq = d * d;
#pragma unroll
    for (int off = 32; off > 0; off >>= 1) sq += __shfl_down(sq, off);
    __shared__ float red[4];
    int lane = tid & 63;
    int wid = tid >> 6;
    if (lane == 0) red[wid] = sq;
    __syncthreads();
    if (tid == 0) bsums[t] = (red[0] + red[1]) + (red[2] + red[3]);
}

// K4: fixed-order reduction of 100 tile SSEs -> loss.
__global__ void __launch_bounds__(64) loss_kernel(const float* __restrict__ bsums,
                                                  float* __restrict__ loss_out) {
    int lane = threadIdx.x;
    float v = 0.0f;
    if (lane < NTILE) v = bsums[lane];
    if (lane + 64 < NTILE) v += bsums[lane + 64];
#pragma unroll
    for (int off = 32; off > 0; off >>= 1) v += __shfl_down(v, off);
    if (lane == 0) loss_out[0] = v;
}

extern "C" void kernel_launch(void* const* d_in, const int* in_sizes, int n_in,
                              void* d_out, int out_size, void* d_ws, size_t ws_size,
                              hipStream_t stream) {
    const float* verts = (const float*)d_in[0];
    const int* faces = (const int*)d_in[1];
    const float* img_ref = (const float*)d_in[2];
    float* out = (float*)d_out;

    // workspace layout (16B aligned)
    float* list = (float*)d_ws;                                   // 100*4096*12 f = 19.66 MB
    float* partials = list + (size_t)NTILE * CAP * 12;            // 100*64*256 f = 6.55 MB
    int* nk_arr = (int*)(partials + (size_t)NTILE * MAXK * 256);  // 100
    int* cumk = nk_arr + 128;                                     // 101 (+pad)
    int* items = cumk + 128;                                      // <= 6400
    float* bsums = (float*)(items + NTILE * MAXK + 128);          // 100

    setup_cull<<<NTILE, 512, 0, stream>>>(verts, faces, list, nk_arr);
    build_items<<<1, 128, 0, stream>>>(nk_arr, cumk, items);
    cover<<<NBLK, 256, 0, stream>>>(list, cumk, items, partials);
    finish<<<NTILE, 256, 0, stream>>>(partials, nk_arr, img_ref, out, bsums);
    loss_kernel<<<1, 64, 0, stream>>>(bsums, out + NPIX);
}